// Round 11
// baseline (70.693 us; speedup 1.0000x reference)
//
#include <hip/hip_runtime.h>
#include <hip/hip_bf16.h>
#include <math.h>

#define H 256
#define BQ 1024
#define NPOOL 32768
#define MAXN 64

typedef __attribute__((ext_vector_type(8))) short short8;
typedef __attribute__((ext_vector_type(8))) unsigned short ushort8v;
typedef __attribute__((ext_vector_type(4))) float f32x4;

__device__ __forceinline__ unsigned short f2bf(float f) {
  unsigned int u = __float_as_uint(f);
  unsigned int r = (u + 0x7fffu + ((u >> 16) & 1u)) >> 16;
  return (unsigned short)r;
}
__device__ __forceinline__ float b2f(unsigned short u) {
  return __uint_as_float((unsigned int)u << 16);
}
__device__ __forceinline__ unsigned int cvt_pk_bf16(float a, float b) {
  unsigned int r;
  asm("v_cvt_pk_bf16_f32 %0, %1, %2" : "=v"(r) : "v"(a), "v"(b));
  return r;
}
__device__ __forceinline__ void gload16(const void* g, void* l) {
  __builtin_amdgcn_global_load_lds(
      (const __attribute__((address_space(1))) unsigned int*)g,
      (__attribute__((address_space(3))) unsigned int*)l, 16, 0, 0);
}

// ---------------------------------------------------------------------------
// prep: transpose Wk/Wv -> bf16 W^T only (32 blocks)
// ---------------------------------------------------------------------------
__global__ __launch_bounds__(256) void prep_kernel(
    const float* __restrict__ Wk, const float* __restrict__ Wv,
    unsigned short* __restrict__ WkT, unsigned short* __restrict__ WvT) {
  __shared__ float ls[64][65];
  const int b = blockIdx.x;
  const int t = threadIdx.x;
  const float* W = (b & 16) ? Wv : Wk;
  unsigned short* WT = (b & 16) ? WvT : WkT;
  const int tile = b & 15;
  const int k0 = (tile >> 2) * 64, c0 = (tile & 3) * 64;
  const int tx = t & 63, ty = t >> 6;
#pragma unroll
  for (int kk = 0; kk < 16; ++kk)
    ls[tx][kk * 4 + ty] = W[(size_t)(k0 + kk * 4 + ty) * H + c0 + tx];
  __syncthreads();
#pragma unroll
  for (int cc = 0; cc < 16; ++cc) {
    const int c = cc * 4 + ty;
    WT[(size_t)(c0 + c) * H + k0 + tx] = f2bf(ls[c][tx]);
  }
}

// ---------------------------------------------------------------------------
// kvproj: one matrix (K or V) per block, 128x128 tile, BK=64, double-buffered
// (64 KB LDS -> 2 blocks/CU -> 4 waves/SIMD). 512 threads, 8 waves.
// A: fp32 soc -> regs -> cvt_pk -> swizzled ds_write. B: global_load_lds.
// K-blocks also compute 2 q-rows in the prologue (hidden under staging).
// bid map: tile = ((bid>>4)<<3)|(bid&7), kv = (bid>>3)&1 -> K/V mates 8 apart
// (same XCD) so the duplicate A fetch L2-hits.
// ---------------------------------------------------------------------------
__global__ __launch_bounds__(512, 4) void kvproj_kernel(
    const float* __restrict__ soc,
    const unsigned short* __restrict__ WkT,
    const unsigned short* __restrict__ WvT,
    const float* __restrict__ bk, const float* __restrict__ bv,
    const float* __restrict__ enc, const float* __restrict__ Wq,
    const float* __restrict__ bq, float* __restrict__ qbuf,
    unsigned short* __restrict__ kout, unsigned short* __restrict__ vout) {
  // A[2][16KB] @ 0 | B[2][16KB] @ 32768
  __shared__ __align__(16) char LDSb[65536];
  const int t = threadIdx.x;
  const int lane = t & 63, wid = t >> 6;
  const int bid = blockIdx.x;
  const int tile = ((bid >> 4) << 3) | (bid & 7);  // 0..511
  const int kv = (bid >> 3) & 1;
  const int brow = (tile >> 1) * 128;
  const int col0 = (tile & 1) * 128;
  const unsigned short* WT = kv ? WvT : WkT;
  const float* bias = kv ? bv : bk;
  unsigned short* outp = kv ? vout : kout;

  const int srow = t >> 3;        // 0..63 (B staging)
  const int slin = t & 7;
  const int arow = t >> 2;        // 0..127 (A staging, 4 thr/row)
  const int sbase = (t & 3) * 2;  // 16B-slot base: 0,2,4,6

  f32x4 acc[2][4];                // [n][m]
#pragma unroll
  for (int n = 0; n < 2; ++n)
#pragma unroll
    for (int m = 0; m < 4; ++m) acc[n][m] = (f32x4)0.f;

  const int wr = wid >> 2, wc = wid & 3;  // 64x32 quadrant per wave

  float4 av[4];
  const float* asrc = soc + (size_t)(brow + arow) * H + sbase * 8;

#define AREG_LOAD(kt)                                                 \
  {                                                                   \
    const float* p_ = asrc + (kt)*64;                                 \
    _Pragma("unroll") for (int s = 0; s < 4; ++s)                     \
        av[s] = *(const float4*)(p_ + s * 4);                         \
  }
#define STAGE_B(kt, pb)                                               \
  {                                                                   \
    const int k0_ = (kt)*64;                                          \
    char* bb_ = LDSb + 32768 + (pb)*16384;                            \
    _Pragma("unroll") for (int c = 0; c < 2; ++c) {                   \
      const int row_ = c * 64 + srow;                                 \
      const int ssrc_ = slin ^ (row_ & 7);                            \
      gload16(WT + (size_t)(col0 + row_) * H + k0_ + ssrc_ * 8,       \
              bb_ + c * 8192 + t * 16);                               \
    }                                                                 \
  }
#define AWRITE(pb)                                                    \
  {                                                                   \
    char* ab_ = LDSb + (pb)*16384;                                    \
    _Pragma("unroll") for (int s = 0; s < 2; ++s) {                   \
      uint4 p;                                                        \
      p.x = cvt_pk_bf16(av[2 * s].x, av[2 * s].y);                    \
      p.y = cvt_pk_bf16(av[2 * s].z, av[2 * s].w);                    \
      p.z = cvt_pk_bf16(av[2 * s + 1].x, av[2 * s + 1].y);            \
      p.w = cvt_pk_bf16(av[2 * s + 1].z, av[2 * s + 1].w);            \
      *(uint4*)(ab_ + arow * 128 + ((sbase + s) ^ (arow & 7)) * 16) = p; \
    }                                                                 \
  }

  // prologue: tile 0 staging in flight
  AREG_LOAD(0);                                      // vm: A0(4)
  STAGE_B(0, 0);                                     // vm: A0(4) B0(2)
  asm volatile("s_waitcnt vmcnt(2)" ::: "memory");   // A0 regs arrived
  AWRITE(0);

  // q-rows 2*tile, 2*tile+1 (K-blocks only) — overlaps with B0 in flight.
  if (kv == 0) {
    const int qrow = 2 * tile + (t >> 8);   // wave-uniform
    const int qcol = t & 255;
    const float* er = enc + (size_t)qrow * H;
    const float* wq = Wq + qcol;
    float qa0 = 0.f, qa1 = 0.f, qa2 = 0.f, qa3 = 0.f;
#pragma unroll 4
    for (int k = 0; k < H; k += 4) {
      qa0 = fmaf(er[k + 0], wq[(size_t)(k + 0) * H], qa0);
      qa1 = fmaf(er[k + 1], wq[(size_t)(k + 1) * H], qa1);
      qa2 = fmaf(er[k + 2], wq[(size_t)(k + 2) * H], qa2);
      qa3 = fmaf(er[k + 3], wq[(size_t)(k + 3) * H], qa3);
    }
    const float qv = fmaxf((qa0 + qa1) + (qa2 + qa3) + bq[qcol], 0.f) * 0.0625f;
    qbuf[(size_t)qrow * H + qcol] = qv;
  }

#pragma unroll
  for (int kt = 0; kt < 4; ++kt) {
    const int cur = kt & 1;
    if (kt < 3) {
      AREG_LOAD(kt + 1);                             // +4
      STAGE_B(kt + 1, cur ^ 1);                      // +2
      asm volatile("s_waitcnt vmcnt(6)" ::: "memory");  // B(kt) landed
    } else {
      asm volatile("s_waitcnt vmcnt(0)" ::: "memory");
    }
    asm volatile("s_waitcnt lgkmcnt(0)" ::: "memory");  // my A-writes drained
    __builtin_amdgcn_s_barrier();                       // half `cur` staged
    const char* Ab = LDSb + cur * 16384;
    const char* Bb = LDSb + 32768 + cur * 16384;
#pragma unroll
    for (int kk = 0; kk < 2; ++kk) {
      short8 af[4], bf[2];
#pragma unroll
      for (int m = 0; m < 4; ++m) {
        const int ar = wr * 64 + m * 16 + (lane & 15);
        const int sl = (kk * 4 + (lane >> 4)) ^ (ar & 7);
        af[m] = *(const short8*)(Ab + ar * 128 + sl * 16);
      }
#pragma unroll
      for (int n = 0; n < 2; ++n) {
        const int br = wc * 32 + n * 16 + (lane & 15);
        const int sl = (kk * 4 + (lane >> 4)) ^ (br & 7);
        bf[n] = *(const short8*)(Bb + br * 128 + sl * 16);
      }
#pragma unroll
      for (int n = 0; n < 2; ++n)
#pragma unroll
        for (int m = 0; m < 4; ++m)
          acc[n][m] = __builtin_amdgcn_mfma_f32_16x16x32_bf16(
              af[m], bf[n], acc[n][m], 0, 0, 0);
    }
    if (kt < 3) {
      asm volatile("s_waitcnt vmcnt(2)" ::: "memory");  // A(kt+1) regs arrived
      AWRITE(cur ^ 1);
    }
    __builtin_amdgcn_s_barrier();  // all done reading half `cur`
  }
#undef AREG_LOAD
#undef STAGE_B
#undef AWRITE

  float bn[2];
#pragma unroll
  for (int n = 0; n < 2; ++n)
    bn[n] = bias[col0 + wc * 32 + n * 16 + (lane & 15)];
#pragma unroll
  for (int n = 0; n < 2; ++n)
#pragma unroll
    for (int m = 0; m < 4; ++m) {
      const int col = col0 + wc * 32 + n * 16 + (lane & 15);
#pragma unroll
      for (int r = 0; r < 4; ++r) {
        const int row = brow + wr * 64 + m * 16 + (lane >> 4) * 4 + r;
        outp[(size_t)row * H + col] = f2bf(fmaxf(acc[n][m][r] + bn[n], 0.f));
      }
    }
}

// ---------------------------------------------------------------------------
// attn: per-sample sliced attention; q fp32, k/v bf16 (unchanged)
// ---------------------------------------------------------------------------
__global__ __launch_bounds__(256) void attn_kernel(
    const float* __restrict__ qb, const unsigned short* __restrict__ kb,
    const unsigned short* __restrict__ vb, const int* __restrict__ starts,
    const int* __restrict__ ends, float* __restrict__ out) {
  __shared__ float sc[MAXN];
  const int row = blockIdx.x, t = threadIdx.x;
  const int lane = t & 63, wave = t >> 6;
  const int start = starts[row];
  const int len = ends[row] - start;  // 1..64

  const int qp = (lane & 31) * 8;
  const float4 qv0 = *(const float4*)(qb + (size_t)row * H + qp);
  const float4 qv1 = *(const float4*)(qb + (size_t)row * H + qp + 4);

  for (int jj = wave * 2; jj < len; jj += 8) {
    const int j0 = jj + (lane >> 5);
    if (j0 < len) {
      const ushort8v k8 =
          *(const ushort8v*)(kb + (size_t)(start + j0) * H + qp);
      float s = qv0.x * b2f(k8[0]) + qv0.y * b2f(k8[1]) +
                qv0.z * b2f(k8[2]) + qv0.w * b2f(k8[3]) +
                qv1.x * b2f(k8[4]) + qv1.y * b2f(k8[5]) +
                qv1.z * b2f(k8[6]) + qv1.w * b2f(k8[7]);
#pragma unroll
      for (int off = 16; off; off >>= 1) s += __shfl_xor(s, off, 64);
      if ((lane & 31) == 0) sc[j0] = s;
    }
  }
  __syncthreads();

  if (t < 64) {
    const float x = (t < len) ? sc[t] : -INFINITY;
    float m = x;
#pragma unroll
    for (int off = 32; off; off >>= 1) m = fmaxf(m, __shfl_xor(m, off, 64));
    const float p = (t < len) ? __expf(x - m) : 0.f;
    float ssum = p;
#pragma unroll
    for (int off = 32; off; off >>= 1) ssum += __shfl_xor(ssum, off, 64);
    sc[t] = p / ssum;
  }
  __syncthreads();

  const unsigned short* vp = vb + (size_t)start * H + t;
  float a0 = 0.f, a1 = 0.f, a2 = 0.f, a3 = 0.f;
  int j = 0;
  for (; j + 3 < len; j += 4) {
    a0 = fmaf(sc[j + 0], b2f(vp[(size_t)(j + 0) * H]), a0);
    a1 = fmaf(sc[j + 1], b2f(vp[(size_t)(j + 1) * H]), a1);
    a2 = fmaf(sc[j + 2], b2f(vp[(size_t)(j + 2) * H]), a2);
    a3 = fmaf(sc[j + 3], b2f(vp[(size_t)(j + 3) * H]), a3);
  }
  for (; j < len; ++j) a0 = fmaf(sc[j], b2f(vp[(size_t)j * H]), a0);
  out[(size_t)row * H + t] = (a0 + a1) + (a2 + a3);
}

// ---------------------------------------------------------------------------
extern "C" void kernel_launch(void* const* d_in, const int* in_sizes, int n_in,
                              void* d_out, int out_size, void* d_ws,
                              size_t ws_size, hipStream_t stream) {
  (void)in_sizes; (void)n_in; (void)out_size; (void)ws_size;
  const float* enc = (const float*)d_in[0];
  const float* soc = (const float*)d_in[1];
  const int* starts = (const int*)d_in[2];
  const int* ends = (const int*)d_in[3];
  const float* Wq = (const float*)d_in[4];
  const float* bq = (const float*)d_in[5];
  const float* Wk = (const float*)d_in[6];
  const float* bk = (const float*)d_in[7];
  const float* Wv = (const float*)d_in[8];
  const float* bv = (const float*)d_in[9];
  float* out = (float*)d_out;

  unsigned short* kb = (unsigned short*)d_ws;            // 16 MB
  unsigned short* vb = kb + (size_t)NPOOL * H;           // 16 MB
  unsigned short* WkT = vb + (size_t)NPOOL * H;          // 128 KB
  unsigned short* WvT = WkT + H * H;                     // 128 KB
  float* qbuf = (float*)(WvT + H * H);                   // 1 MB

  prep_kernel<<<32, 256, 0, stream>>>(Wk, Wv, WkT, WvT);
  kvproj_kernel<<<1024, 512, 0, stream>>>(
      soc, WkT, WvT, bk, bv, enc, Wq, bq, qbuf, kb, vb);
  attn_kernel<<<BQ, 256, 0, stream>>>(qbuf, kb, vb, starts, ends, out);
}

// Round 12
// 62.587 us; speedup vs baseline: 1.1295x; 1.1295x over previous
//
#include <hip/hip_runtime.h>
#include <hip/hip_bf16.h>
#include <math.h>

#define H 256
#define BQ 1024
#define NPOOL 32768
#define MAXN 64

#define TRANS_BLOCKS 32    // 2 matrices x 16 tiles of 64x64
#define QPROJ_BLOCKS 256   // BQ/4

typedef __attribute__((ext_vector_type(8))) short short8;
typedef __attribute__((ext_vector_type(8))) unsigned short ushort8v;
typedef __attribute__((ext_vector_type(4))) float f32x4;

__device__ __forceinline__ unsigned short f2bf(float f) {
  unsigned int u = __float_as_uint(f);
  unsigned int r = (u + 0x7fffu + ((u >> 16) & 1u)) >> 16;
  return (unsigned short)r;
}
__device__ __forceinline__ float b2f(unsigned short u) {
  return __uint_as_float((unsigned int)u << 16);
}
__device__ __forceinline__ unsigned int cvt_pk_bf16(float a, float b) {
  unsigned int r;
  asm("v_cvt_pk_bf16_f32 %0, %1, %2" : "=v"(r) : "v"(a), "v"(b));
  return r;
}
__device__ __forceinline__ void gload16(const void* g, void* l) {
  __builtin_amdgcn_global_load_lds(
      (const __attribute__((address_space(1))) unsigned int*)g,
      (__attribute__((address_space(3))) unsigned int*)l, 16, 0, 0);
}

// ---------------------------------------------------------------------------
// prep: [0,32) transpose Wk/Wv->bf16 | [32,288) qproj (4 rows/block)
// (r10 version, proven)
// ---------------------------------------------------------------------------
__global__ __launch_bounds__(256) void prep_kernel(
    const float* __restrict__ Wk, const float* __restrict__ Wv,
    unsigned short* __restrict__ WkT, unsigned short* __restrict__ WvT,
    const float* __restrict__ enc, const float* __restrict__ Wq,
    const float* __restrict__ bq, float* __restrict__ qbuf) {
  __shared__ float smem[64 * 65];
  const int b = blockIdx.x;
  const int t = threadIdx.x;

  if (b < TRANS_BLOCKS) {
    const float* W = (b & 16) ? Wv : Wk;
    unsigned short* WT = (b & 16) ? WvT : WkT;
    const int tile = b & 15;
    const int k0 = (tile >> 2) * 64, c0 = (tile & 3) * 64;
    const int tx = t & 63, ty = t >> 6;
    float (*ls)[65] = (float(*)[65])smem;
#pragma unroll
    for (int kk = 0; kk < 16; ++kk)
      ls[tx][kk * 4 + ty] = W[(size_t)(k0 + kk * 4 + ty) * H + c0 + tx];
    __syncthreads();
#pragma unroll
    for (int cc = 0; cc < 16; ++cc) {
      const int c = cc * 4 + ty;
      WT[(size_t)(c0 + c) * H + k0 + tx] = f2bf(ls[c][tx]);
    }
  } else {
    const int bb = b - TRANS_BLOCKS;
    const int row0 = bb * 4;
    float (*xs)[H] = (float(*)[H])smem;
    {
      float4 v = *(const float4*)(enc + (size_t)(row0 + (t >> 6)) * H + (t & 63) * 4);
      *(float4*)(&xs[t >> 6][(t & 63) * 4]) = v;
    }
    __syncthreads();
    float acc[4] = {0.f, 0.f, 0.f, 0.f};
#pragma unroll 4
    for (int k = 0; k < H; ++k) {
      const float w = Wq[(size_t)k * H + t];
#pragma unroll
      for (int r = 0; r < 4; ++r) acc[r] = fmaf(xs[r][k], w, acc[r]);
    }
    const float bias = bq[t];
#pragma unroll
    for (int r = 0; r < 4; ++r)
      qbuf[(size_t)(row0 + r) * H + t] = fmaxf(acc[r] + bias, 0.f) * 0.0625f;
  }
}

// ---------------------------------------------------------------------------
// kvproj: K AND V per block, 128x128 tile, BK=32, double-buffered.
// LDS 48 KB -> 2 blocks/CU (4 waves/SIMD). 512 threads.
// A: fp32 soc -> regs -> cvt_pk -> swizzled ds_write. B: global_load_lds
// with pre-swizzled source. Counted vmcnt, raw barriers.
// Slot swizzle (64B rows, 4 slots): slot ^ (row&3)^((row>>2)&3).
// ---------------------------------------------------------------------------
__global__ __launch_bounds__(512, 4) void kvproj_kernel(
    const float* __restrict__ soc,
    const unsigned short* __restrict__ WkT,
    const unsigned short* __restrict__ WvT,
    const float* __restrict__ bk, const float* __restrict__ bv,
    unsigned short* __restrict__ kout, unsigned short* __restrict__ vout) {
  // A[2][8KB] @0 | Bk[2][8KB] @16384 | Bv[2][8KB] @32768  = 48 KB
  __shared__ __align__(16) char LDSb[49152];
  const int t = threadIdx.x;
  const int lane = t & 63, wid = t >> 6;
  const int bid = blockIdx.x;
  const int bx = ((bid >> 4) << 3) | (bid & 7);  // 0..255
  const int by = (bid >> 3) & 1;
  const int brow = bx * 128;
  const int col0 = by * 128;

  const int srow = t >> 2;        // 0..127 (both A and B staging rows)
  const int slin = t & 3;         // linear 16B slot
  const int ssw = slin ^ ((srow & 3) ^ ((srow >> 2) & 3));  // swizzled slot

  f32x4 accK[2][4], accV[2][4];   // [n][m]
#pragma unroll
  for (int n = 0; n < 2; ++n)
#pragma unroll
    for (int m = 0; m < 4; ++m) { accK[n][m] = (f32x4)0.f; accV[n][m] = (f32x4)0.f; }

  const int wr = wid >> 2, wc = wid & 3;  // 64x32 output quadrant per wave

  float4 av[2];
  const float* asrc = soc + (size_t)(brow + srow) * H + slin * 8;

  // A(kt): 2 x float4 (8 fp32 = one 16B bf16 slot after cvt)
#define AREG_LOAD(kt)                                                 \
  {                                                                   \
    const float* p_ = asrc + (kt)*32;                                 \
    av[0] = *(const float4*)(p_);                                     \
    av[1] = *(const float4*)(p_ + 4);                                 \
  }
  // B(kt) -> half pb: 1 gload16 per matrix, pre-swizzled source
#define STAGE_B(kt, pb)                                               \
  {                                                                   \
    const int k0_ = (kt)*32;                                          \
    gload16(WkT + (size_t)(col0 + srow) * H + k0_ + ssw * 8,          \
            LDSb + 16384 + (pb)*8192 + t * 16);                       \
    gload16(WvT + (size_t)(col0 + srow) * H + k0_ + ssw * 8,          \
            LDSb + 32768 + (pb)*8192 + t * 16);                       \
  }
  // cvt av -> one 16B slot, swizzled ds_write into half pb
#define AWRITE(pb)                                                    \
  {                                                                   \
    uint4 p;                                                          \
    p.x = cvt_pk_bf16(av[0].x, av[0].y);                              \
    p.y = cvt_pk_bf16(av[0].z, av[0].w);                              \
    p.z = cvt_pk_bf16(av[1].x, av[1].y);                              \
    p.w = cvt_pk_bf16(av[1].z, av[1].w);                              \
    *(uint4*)(LDSb + (pb)*8192 + srow * 64 + ssw * 16) = p;           \
  }

  // prologue: tile 0
  AREG_LOAD(0);                                      // vm: A0(2)
  STAGE_B(0, 0);                                     // vm: A0(2) B0(2)
  asm volatile("s_waitcnt vmcnt(2)" ::: "memory");   // A0 regs arrived
  AWRITE(0);

#pragma unroll
  for (int kt = 0; kt < 8; ++kt) {
    const int cur = kt & 1;
    if (kt < 7) {
      AREG_LOAD(kt + 1);                             // +2
      STAGE_B(kt + 1, cur ^ 1);                      // +2 -> B(kt)=oldest 2
      asm volatile("s_waitcnt vmcnt(4)" ::: "memory");  // B(kt) landed
    } else {
      asm volatile("s_waitcnt vmcnt(0)" ::: "memory");
    }
    asm volatile("s_waitcnt lgkmcnt(0)" ::: "memory");  // my A-writes drained
    __builtin_amdgcn_s_barrier();                       // half `cur` staged
    const char* Ab = LDSb + cur * 8192;
    const char* Bkb = LDSb + 16384 + cur * 8192;
    const char* Bvb = LDSb + 32768 + cur * 8192;
    {
      short8 af[4], bkf[2], bvf[2];
#pragma unroll
      for (int m = 0; m < 4; ++m) {
        const int ar = wr * 64 + m * 16 + (lane & 15);
        const int sl = (lane >> 4) ^ ((ar & 3) ^ ((ar >> 2) & 3));
        af[m] = *(const short8*)(Ab + ar * 64 + sl * 16);
      }
#pragma unroll
      for (int n = 0; n < 2; ++n) {
        const int br = wc * 32 + n * 16 + (lane & 15);
        const int sl = (lane >> 4) ^ ((br & 3) ^ ((br >> 2) & 3));
        bkf[n] = *(const short8*)(Bkb + br * 64 + sl * 16);
        bvf[n] = *(const short8*)(Bvb + br * 64 + sl * 16);
      }
#pragma unroll
      for (int n = 0; n < 2; ++n)
#pragma unroll
        for (int m = 0; m < 4; ++m) {
          accK[n][m] = __builtin_amdgcn_mfma_f32_16x16x32_bf16(
              af[m], bkf[n], accK[n][m], 0, 0, 0);
          accV[n][m] = __builtin_amdgcn_mfma_f32_16x16x32_bf16(
              af[m], bvf[n], accV[n][m], 0, 0, 0);
        }
    }
    if (kt < 7) {
      asm volatile("s_waitcnt vmcnt(2)" ::: "memory");  // A(kt+1) regs arrived
      AWRITE(cur ^ 1);
    }
    __builtin_amdgcn_s_barrier();  // all done reading half `cur`
  }
#undef AREG_LOAD
#undef STAGE_B
#undef AWRITE

  float bkn[2], bvn[2];
#pragma unroll
  for (int n = 0; n < 2; ++n) {
    const int col = col0 + wc * 32 + n * 16 + (lane & 15);
    bkn[n] = bk[col]; bvn[n] = bv[col];
  }
#pragma unroll
  for (int n = 0; n < 2; ++n)
#pragma unroll
    for (int m = 0; m < 4; ++m) {
      const int col = col0 + wc * 32 + n * 16 + (lane & 15);
#pragma unroll
      for (int r = 0; r < 4; ++r) {
        const int row = brow + wr * 64 + m * 16 + (lane >> 4) * 4 + r;
        kout[(size_t)row * H + col] = f2bf(fmaxf(accK[n][m][r] + bkn[n], 0.f));
        vout[(size_t)row * H + col] = f2bf(fmaxf(accV[n][m][r] + bvn[n], 0.f));
      }
    }
}

// ---------------------------------------------------------------------------
// attn: per-sample sliced attention; q fp32, k/v bf16 (unchanged)
// ---------------------------------------------------------------------------
__global__ __launch_bounds__(256) void attn_kernel(
    const float* __restrict__ qb, const unsigned short* __restrict__ kb,
    const unsigned short* __restrict__ vb, const int* __restrict__ starts,
    const int* __restrict__ ends, float* __restrict__ out) {
  __shared__ float sc[MAXN];
  const int row = blockIdx.x, t = threadIdx.x;
  const int lane = t & 63, wave = t >> 6;
  const int start = starts[row];
  const int len = ends[row] - start;  // 1..64

  const int qp = (lane & 31) * 8;
  const float4 qv0 = *(const float4*)(qb + (size_t)row * H + qp);
  const float4 qv1 = *(const float4*)(qb + (size_t)row * H + qp + 4);

  for (int jj = wave * 2; jj < len; jj += 8) {
    const int j0 = jj + (lane >> 5);
    if (j0 < len) {
      const ushort8v k8 =
          *(const ushort8v*)(kb + (size_t)(start + j0) * H + qp);
      float s = qv0.x * b2f(k8[0]) + qv0.y * b2f(k8[1]) +
                qv0.z * b2f(k8[2]) + qv0.w * b2f(k8[3]) +
                qv1.x * b2f(k8[4]) + qv1.y * b2f(k8[5]) +
                qv1.z * b2f(k8[6]) + qv1.w * b2f(k8[7]);
#pragma unroll
      for (int off = 16; off; off >>= 1) s += __shfl_xor(s, off, 64);
      if ((lane & 31) == 0) sc[j0] = s;
    }
  }
  __syncthreads();

  if (t < 64) {
    const float x = (t < len) ? sc[t] : -INFINITY;
    float m = x;
#pragma unroll
    for (int off = 32; off; off >>= 1) m = fmaxf(m, __shfl_xor(m, off, 64));
    const float p = (t < len) ? __expf(x - m) : 0.f;
    float ssum = p;
#pragma unroll
    for (int off = 32; off; off >>= 1) ssum += __shfl_xor(ssum, off, 64);
    sc[t] = p / ssum;
  }
  __syncthreads();

  const unsigned short* vp = vb + (size_t)start * H + t;
  float a0 = 0.f, a1 = 0.f, a2 = 0.f, a3 = 0.f;
  int j = 0;
  for (; j + 3 < len; j += 4) {
    a0 = fmaf(sc[j + 0], b2f(vp[(size_t)(j + 0) * H]), a0);
    a1 = fmaf(sc[j + 1], b2f(vp[(size_t)(j + 1) * H]), a1);
    a2 = fmaf(sc[j + 2], b2f(vp[(size_t)(j + 2) * H]), a2);
    a3 = fmaf(sc[j + 3], b2f(vp[(size_t)(j + 3) * H]), a3);
  }
  for (; j < len; ++j) a0 = fmaf(sc[j], b2f(vp[(size_t)j * H]), a0);
  out[(size_t)row * H + t] = (a0 + a1) + (a2 + a3);
}

// ---------------------------------------------------------------------------
extern "C" void kernel_launch(void* const* d_in, const int* in_sizes, int n_in,
                              void* d_out, int out_size, void* d_ws,
                              size_t ws_size, hipStream_t stream) {
  (void)in_sizes; (void)n_in; (void)out_size; (void)ws_size;
  const float* enc = (const float*)d_in[0];
  const float* soc = (const float*)d_in[1];
  const int* starts = (const int*)d_in[2];
  const int* ends = (const int*)d_in[3];
  const float* Wq = (const float*)d_in[4];
  const float* bq = (const float*)d_in[5];
  const float* Wk = (const float*)d_in[6];
  const float* bk = (const float*)d_in[7];
  const float* Wv = (const float*)d_in[8];
  const float* bv = (const float*)d_in[9];
  float* out = (float*)d_out;

  unsigned short* kb = (unsigned short*)d_ws;            // 16 MB
  unsigned short* vb = kb + (size_t)NPOOL * H;           // 16 MB
  unsigned short* WkT = vb + (size_t)NPOOL * H;          // 128 KB
  unsigned short* WvT = WkT + H * H;                     // 128 KB
  float* qbuf = (float*)(WvT + H * H);                   // 1 MB

  prep_kernel<<<TRANS_BLOCKS + QPROJ_BLOCKS, 256, 0, stream>>>(
      Wk, Wv, WkT, WvT, enc, Wq, bq, qbuf);
  kvproj_kernel<<<512, 512, 0, stream>>>(
      soc, WkT, WvT, bk, bv, kb, vb);
  attn_kernel<<<BQ, 256, 0, stream>>>(qbuf, kb, vb, starts, ends, out);
}

// Round 14
// 48.857 us; speedup vs baseline: 1.4469x; 1.2810x over previous
//
#include <hip/hip_runtime.h>
#include <hip/hip_bf16.h>
#include <math.h>

#define H 256
#define BQ 1024
#define NPOOL 32768
#define MAXN 64

typedef __attribute__((ext_vector_type(8))) short short8;
typedef __attribute__((ext_vector_type(8))) unsigned short ushort8v;
typedef __attribute__((ext_vector_type(4))) float f32x4;

__device__ __forceinline__ unsigned short f2bf(float f) {
  unsigned int u = __float_as_uint(f);
  unsigned int r = (u + 0x7fffu + ((u >> 16) & 1u)) >> 16;
  return (unsigned short)r;
}
__device__ __forceinline__ float b2f(unsigned short u) {
  return __uint_as_float((unsigned int)u << 16);
}
__device__ __forceinline__ unsigned int cvt_pk_bf16(float a, float b) {
  unsigned int r;
  asm("v_cvt_pk_bf16_f32 %0, %1, %2" : "=v"(r) : "v"(a), "v"(b));
  return r;
}
__device__ __forceinline__ void gload16(const void* g, void* l) {
  __builtin_amdgcn_global_load_lds(
      (const __attribute__((address_space(1))) unsigned int*)g,
      (__attribute__((address_space(3))) unsigned int*)l, 16, 0, 0);
}

// ---------------------------------------------------------------------------
// prep: transpose Wq(+scale)/Wk/Wv -> bf16 W^T (48 blocks); b<4 blocks also
// write bqs = bq * 0.0625 (scale folded: q = relu(enc@(Wq/16)+bq/16)).
// ---------------------------------------------------------------------------
__global__ __launch_bounds__(256) void prep_kernel(
    const float* __restrict__ Wq, const float* __restrict__ Wk,
    const float* __restrict__ Wv, const float* __restrict__ bq,
    unsigned short* __restrict__ WqT, unsigned short* __restrict__ WkT,
    unsigned short* __restrict__ WvT, float* __restrict__ bqs) {
  __shared__ float ls[64][65];
  const int b = blockIdx.x;
  const int t = threadIdx.x;
  const float* W = (b < 16) ? Wq : ((b < 32) ? Wk : Wv);
  unsigned short* WT = (b < 16) ? WqT : ((b < 32) ? WkT : WvT);
  const float scale = (b < 16) ? 0.0625f : 1.0f;
  const int tile = b & 15;
  const int k0 = (tile >> 2) * 64, c0 = (tile & 3) * 64;
  const int tx = t & 63, ty = t >> 6;
#pragma unroll
  for (int kk = 0; kk < 16; ++kk)
    ls[tx][kk * 4 + ty] = W[(size_t)(k0 + kk * 4 + ty) * H + c0 + tx];
  __syncthreads();
#pragma unroll
  for (int cc = 0; cc < 16; ++cc) {
    const int c = cc * 4 + ty;
    WT[(size_t)(c0 + c) * H + k0 + tx] = f2bf(ls[c][tx] * scale);
  }
  if (b < 4 && t < 64) bqs[c0 + t] = bq[c0 + t] * 0.0625f;
}

// ---------------------------------------------------------------------------
// gemm: unified QKV projection. r10 geometry: 128x128 tile, BK=64, 96 KB LDS
// double-buffer, 512 threads (8 waves), counted vmcnt, raw barriers;
// A fp32->regs->cvt_pk->swizzled ds_write, B via global_load_lds.
// bid<512: K&V tiles of soc (256 row-tiles x 2 col-tiles, XCD-paired map).
// bid>=512: 16 q tiles of enc (Bk=Bv=WqT -> qbf, value written twice, benign).
// ---------------------------------------------------------------------------
__global__ __launch_bounds__(512) void gemm_kernel(
    const float* __restrict__ soc, const float* __restrict__ enc,
    const unsigned short* __restrict__ WkT,
    const unsigned short* __restrict__ WvT,
    const unsigned short* __restrict__ WqT,
    const float* __restrict__ bk, const float* __restrict__ bv,
    const float* __restrict__ bqs,
    unsigned short* __restrict__ kout, unsigned short* __restrict__ vout,
    unsigned short* __restrict__ qout) {
  // A[2][16KB] | Bk[2][16KB] | Bv[2][16KB] = 96 KB
  __shared__ __align__(16) char LDSb[98304];
  const int t = threadIdx.x;
  const int lane = t & 63, wid = t >> 6;
  const int bid = blockIdx.x;
  const bool isQ = bid >= 512;
  int brow, col0;
  if (isQ) {
    const int tl = bid - 512;            // 0..15
    brow = (tl >> 1) * 128;              // 8 row-tiles of enc
    col0 = (tl & 1) * 128;
  } else {
    const int bx = ((bid >> 4) << 3) | (bid & 7);  // 0..255 row-tile
    const int by = (bid >> 3) & 1;                 // col-tile; mates 8 apart
    brow = bx * 128;
    col0 = by * 128;
  }
  const float* Asrc = isQ ? enc : soc;
  const unsigned short* Bkg = isQ ? WqT : WkT;
  const unsigned short* Bvg = isQ ? WqT : WvT;
  const float* biask = isQ ? bqs : bk;
  const float* biasv = isQ ? bqs : bv;
  unsigned short* outk = isQ ? qout : kout;
  unsigned short* outv = isQ ? qout : vout;

  const int srow = t >> 3;        // 0..63 (B staging)
  const int slin = t & 7;
  const int arow = t >> 2;        // 0..127 (A staging, 4 thr/row)
  const int sbase = (t & 3) * 2;  // 16B-slot base: 0,2,4,6

  f32x4 accK[2][4], accV[2][4];   // [n][m]
#pragma unroll
  for (int n = 0; n < 2; ++n)
#pragma unroll
    for (int m = 0; m < 4; ++m) { accK[n][m] = (f32x4)0.f; accV[n][m] = (f32x4)0.f; }

  const int wr = wid >> 2, wc = wid & 3;  // 64x32 output quadrant per wave

  float4 av[4];
  const float* asrc = Asrc + (size_t)(brow + arow) * H + sbase * 8;

#define AREG_LOAD(kt)                                                 \
  {                                                                   \
    const float* p_ = asrc + (kt)*64;                                 \
    _Pragma("unroll") for (int s = 0; s < 4; ++s)                     \
        av[s] = *(const float4*)(p_ + s * 4);                         \
  }
#define STAGE_B(kt, pb)                                               \
  {                                                                   \
    const int k0_ = (kt)*64;                                          \
    char* bk_ = LDSb + 32768 + (pb)*16384;                            \
    char* bv_ = LDSb + 65536 + (pb)*16384;                            \
    _Pragma("unroll") for (int c = 0; c < 2; ++c) {                   \
      const int row_ = c * 64 + srow;                                 \
      const int ssrc_ = slin ^ (row_ & 7);                            \
      gload16(Bkg + (size_t)(col0 + row_) * H + k0_ + ssrc_ * 8,      \
              bk_ + c * 8192 + t * 16);                               \
      gload16(Bvg + (size_t)(col0 + row_) * H + k0_ + ssrc_ * 8,      \
              bv_ + c * 8192 + t * 16);                               \
    }                                                                 \
  }
#define AWRITE(pb)                                                    \
  {                                                                   \
    char* ab_ = LDSb + (pb)*16384;                                    \
    _Pragma("unroll") for (int s = 0; s < 2; ++s) {                   \
      uint4 p;                                                        \
      p.x = cvt_pk_bf16(av[2 * s].x, av[2 * s].y);                    \
      p.y = cvt_pk_bf16(av[2 * s].z, av[2 * s].w);                    \
      p.z = cvt_pk_bf16(av[2 * s + 1].x, av[2 * s + 1].y);            \
      p.w = cvt_pk_bf16(av[2 * s + 1].z, av[2 * s + 1].w);            \
      *(uint4*)(ab_ + arow * 128 + ((sbase + s) ^ (arow & 7)) * 16) = p; \
    }                                                                 \
  }

  // prologue: tile 0
  AREG_LOAD(0);                                      // vm: A0(4)
  STAGE_B(0, 0);                                     // vm: A0(4) B0(4)
  asm volatile("s_waitcnt vmcnt(4)" ::: "memory");   // A0 regs arrived
  AWRITE(0);

#pragma unroll
  for (int kt = 0; kt < 4; ++kt) {
    const int cur = kt & 1;
    if (kt < 3) {
      AREG_LOAD(kt + 1);                             // +4
      STAGE_B(kt + 1, cur ^ 1);                      // +4 -> B(kt)=oldest 4
      asm volatile("s_waitcnt vmcnt(8)" ::: "memory");  // B(kt) landed
    } else {
      asm volatile("s_waitcnt vmcnt(0)" ::: "memory");
    }
    asm volatile("s_waitcnt lgkmcnt(0)" ::: "memory");  // my A-writes drained
    __builtin_amdgcn_s_barrier();                       // half `cur` staged
    const char* Ab = LDSb + cur * 16384;
    const char* Bkb = LDSb + 32768 + cur * 16384;
    const char* Bvb = LDSb + 65536 + cur * 16384;
#pragma unroll
    for (int kk = 0; kk < 2; ++kk) {
      short8 af[4], bkf[2], bvf[2];
#pragma unroll
      for (int m = 0; m < 4; ++m) {
        const int ar = wr * 64 + m * 16 + (lane & 15);
        const int sl = (kk * 4 + (lane >> 4)) ^ (ar & 7);
        af[m] = *(const short8*)(Ab + ar * 128 + sl * 16);
      }
#pragma unroll
      for (int n = 0; n < 2; ++n) {
        const int br = wc * 32 + n * 16 + (lane & 15);
        const int sl = (kk * 4 + (lane >> 4)) ^ (br & 7);
        bkf[n] = *(const short8*)(Bkb + br * 128 + sl * 16);
        bvf[n] = *(const short8*)(Bvb + br * 128 + sl * 16);
      }
#pragma unroll
      for (int n = 0; n < 2; ++n)
#pragma unroll
        for (int m = 0; m < 4; ++m) {
          accK[n][m] = __builtin_amdgcn_mfma_f32_16x16x32_bf16(
              af[m], bkf[n], accK[n][m], 0, 0, 0);
          accV[n][m] = __builtin_amdgcn_mfma_f32_16x16x32_bf16(
              af[m], bvf[n], accV[n][m], 0, 0, 0);
        }
    }
    if (kt < 3) {
      asm volatile("s_waitcnt vmcnt(4)" ::: "memory");  // A(kt+1) regs arrived
      AWRITE(cur ^ 1);
    }
    __builtin_amdgcn_s_barrier();  // all done reading half `cur`
  }
#undef AREG_LOAD
#undef STAGE_B
#undef AWRITE

  float bkn[2], bvn[2];
#pragma unroll
  for (int n = 0; n < 2; ++n) {
    const int col = col0 + wc * 32 + n * 16 + (lane & 15);
    bkn[n] = biask[col]; bvn[n] = biasv[col];
  }
#pragma unroll
  for (int n = 0; n < 2; ++n)
#pragma unroll
    for (int m = 0; m < 4; ++m) {
      const int col = col0 + wc * 32 + n * 16 + (lane & 15);
#pragma unroll
      for (int r = 0; r < 4; ++r) {
        const int row = brow + wr * 64 + m * 16 + (lane >> 4) * 4 + r;
        outk[(size_t)row * H + col] = f2bf(fmaxf(accK[n][m][r] + bkn[n], 0.f));
        outv[(size_t)row * H + col] = f2bf(fmaxf(accV[n][m][r] + bvn[n], 0.f));
      }
    }
}

// ---------------------------------------------------------------------------
// attn: per-sample sliced attention; q, k, v all bf16
// ---------------------------------------------------------------------------
__global__ __launch_bounds__(256) void attn_kernel(
    const unsigned short* __restrict__ qb,
    const unsigned short* __restrict__ kb,
    const unsigned short* __restrict__ vb, const int* __restrict__ starts,
    const int* __restrict__ ends, float* __restrict__ out) {
  __shared__ float sc[MAXN];
  const int row = blockIdx.x, t = threadIdx.x;
  const int lane = t & 63, wave = t >> 6;
  const int start = starts[row];
  const int len = ends[row] - start;  // 1..64

  const int qp = (lane & 31) * 8;
  const ushort8v q8 = *(const ushort8v*)(qb + (size_t)row * H + qp);
  float qf[8];
#pragma unroll
  for (int e = 0; e < 8; ++e) qf[e] = b2f(q8[e]);

  for (int jj = wave * 2; jj < len; jj += 8) {
    const int j0 = jj + (lane >> 5);
    if (j0 < len) {
      const ushort8v k8 =
          *(const ushort8v*)(kb + (size_t)(start + j0) * H + qp);
      float s = qf[0] * b2f(k8[0]) + qf[1] * b2f(k8[1]) +
                qf[2] * b2f(k8[2]) + qf[3] * b2f(k8[3]) +
                qf[4] * b2f(k8[4]) + qf[5] * b2f(k8[5]) +
                qf[6] * b2f(k8[6]) + qf[7] * b2f(k8[7]);
#pragma unroll
      for (int off = 16; off; off >>= 1) s += __shfl_xor(s, off, 64);
      if ((lane & 31) == 0) sc[j0] = s;
    }
  }
  __syncthreads();

  if (t < 64) {
    const float x = (t < len) ? sc[t] : -INFINITY;
    float m = x;
#pragma unroll
    for (int off = 32; off; off >>= 1) m = fmaxf(m, __shfl_xor(m, off, 64));
    const float p = (t < len) ? __expf(x - m) : 0.f;
    float ssum = p;
#pragma unroll
    for (int off = 32; off; off >>= 1) ssum += __shfl_xor(ssum, off, 64);
    sc[t] = p / ssum;
  }
  __syncthreads();

  const unsigned short* vp = vb + (size_t)start * H + t;
  float a0 = 0.f, a1 = 0.f, a2 = 0.f, a3 = 0.f;
  int j = 0;
  for (; j + 3 < len; j += 4) {
    a0 = fmaf(sc[j + 0], b2f(vp[(size_t)(j + 0) * H]), a0);
    a1 = fmaf(sc[j + 1], b2f(vp[(size_t)(j + 1) * H]), a1);
    a2 = fmaf(sc[j + 2], b2f(vp[(size_t)(j + 2) * H]), a2);
    a3 = fmaf(sc[j + 3], b2f(vp[(size_t)(j + 3) * H]), a3);
  }
  for (; j < len; ++j) a0 = fmaf(sc[j], b2f(vp[(size_t)j * H]), a0);
  out[(size_t)row * H + t] = (a0 + a1) + (a2 + a3);
}

// ---------------------------------------------------------------------------
extern "C" void kernel_launch(void* const* d_in, const int* in_sizes, int n_in,
                              void* d_out, int out_size, void* d_ws,
                              size_t ws_size, hipStream_t stream) {
  (void)in_sizes; (void)n_in; (void)out_size; (void)ws_size;
  const float* enc = (const float*)d_in[0];
  const float* soc = (const float*)d_in[1];
  const int* starts = (const int*)d_in[2];
  const int* ends = (const int*)d_in[3];
  const float* Wq = (const float*)d_in[4];
  const float* bq = (const float*)d_in[5];
  const float* Wk = (const float*)d_in[6];
  const float* bk = (const float*)d_in[7];
  const float* Wv = (const float*)d_in[8];
  const float* bv = (const float*)d_in[9];
  float* out = (float*)d_out;

  unsigned short* kb = (unsigned short*)d_ws;            // 16 MB
  unsigned short* vb = kb + (size_t)NPOOL * H;           // 16 MB
  unsigned short* WkT = vb + (size_t)NPOOL * H;          // 128 KB
  unsigned short* WvT = WkT + H * H;                     // 128 KB
  unsigned short* WqT = WvT + H * H;                     // 128 KB
  unsigned short* qbf = WqT + H * H;                     // 512 KB (BQ*H bf16)
  float* bqs = (float*)(qbf + (size_t)BQ * H);           // 1 KB

  prep_kernel<<<48, 256, 0, stream>>>(Wq, Wk, Wv, bq, WqT, WkT, WvT, bqs);
  gemm_kernel<<<528, 512, 0, stream>>>(soc, enc, WkT, WvT, WqT, bk, bv, bqs,
                                       kb, vb, qbf);
  attn_kernel<<<BQ, 256, 0, stream>>>(qbf, kb, vb, starts, ends, out);
}